// Round 1
// 132.308 us; speedup vs baseline: 1.0445x; 1.0445x over previous
//
#include <hip/hip_runtime.h>
#include <math.h>

// Single-head causal attention, MFMA bf16 pipeline (R10).
//   x:[8,2048,1024] f32, Wq/Wk/Wv:[1024,64] f32, zero_mask:[8,2048] i32
//   out:[8,2048,64] f32
// wcvt: Wt[192][1024] bf16 (B-operand layout)
// qkv : 512 blocks (rowtiles) x 256 thr, 32 rows x 192 cols each (single
//       pass over X: 64 MB read ONCE, was 2x). X dbuf 16 KB + W dbuf 48 KB
//       = 64 KB LDS -> 2 blocks/CU. DMA staging XOR-swizzled.
// attn: 64 q-rows/block, 4 waves, dbuf K/V via swizzled DMA. Halved
//       tile-iterations vs 32-row blocks (4224 vs 8448): half the barriers
//       and half the K/V DMA per unit work. Split-K chunks of 8 tiles,
//       grid (8,32,4). No-max softmax is additive; exp2 with log2e folded
//       into the q scale (native v_exp_f32, no mul).
// comb: rows >= 512 sum ns=ceil(nkt/8) in {2..4} partials, normalize, zmask.
//
// MFMA 16x16x32 layouts (HW-verified):
//   A[m][k]: m = lane&15, k = (lane>>4)*8 + j
//   B[k][n]: n = lane&15, k = (lane>>4)*8 + j
//   C/D:     col = lane&15, row = (lane>>4)*4 + reg
//
// Swizzles (reader applies same XOR as the DMA source permutation):
//   W row (64 bf16 = 8 granules):  slot = g ^ (nloc & 7)
//   X row (64 fp32 = 16 granules): slot = g ^ (row & 15)

#define B_ 8
#define C_ 2048
#define E_ 1024
#define H_ 64
// 2048^-0.5 * log2(e): scores are computed in the log2 domain -> v_exp_f32
#define SCALE (0.02209708691207961f * 1.4426950408889634f)

typedef __attribute__((ext_vector_type(8))) short short8;
typedef __attribute__((ext_vector_type(4))) float floatx4;

union BF8 { short8 s8; unsigned int u[4]; };

static __device__ __forceinline__ unsigned int pack_bf2(float lo, float hi) {
    unsigned int a = __builtin_bit_cast(unsigned int, lo);
    unsigned int b = __builtin_bit_cast(unsigned int, hi);
    return (a >> 16) | (b & 0xFFFF0000u);
}
static __device__ __forceinline__ unsigned short f2bf(float f) {
    return (unsigned short)(__builtin_bit_cast(unsigned int, f) >> 16);
}
static __device__ __forceinline__ void load_lds16(const void* g, void* l) {
    __builtin_amdgcn_global_load_lds(
        (const __attribute__((address_space(1))) void*)g,
        (__attribute__((address_space(3))) void*)l, 16, 0, 0);
}

// ---------------------------------------------------------------------------
// Wt[n=192][k=1024] bf16 from Wq/Wk/Wv[k][64] f32. 48 blocks.
// ---------------------------------------------------------------------------
__global__ __launch_bounds__(256) void wcvt_kernel(
    const float* __restrict__ Wq, const float* __restrict__ Wk,
    const float* __restrict__ Wv, unsigned short* __restrict__ wt)
{
    __shared__ float lds[64][68];
    const int bid = (int)blockIdx.x;
    const int m = bid >> 4, kt = bid & 15, k0 = kt * 64;
    const float* W = (m == 0) ? Wq : (m == 1) ? Wk : Wv;
    const int t = (int)threadIdx.x;
#pragma unroll
    for (int j = 0; j < 4; j++) {
        int idx4 = j * 256 + t;
        int row = idx4 >> 4, c4 = idx4 & 15;
        float4 v = *(const float4*)(W + (size_t)(k0 + row) * 64 + c4 * 4);
        *(float4*)&lds[row][c4 * 4] = v;
    }
    __syncthreads();
#pragma unroll
    for (int j = 0; j < 2; j++) {
        int g = j * 256 + t;
        int n = g >> 3, kk = (g & 7) * 8;
        unsigned int o[4];
#pragma unroll
        for (int i = 0; i < 4; i++)
            o[i] = pack_bf2(lds[kk + 2 * i][n], lds[kk + 2 * i + 1][n]);
        *(uint4*)(wt + (size_t)(m * 64 + n) * 1024 + k0 + kk) =
            make_uint4(o[0], o[1], o[2], o[3]);
    }
}

// ---------------------------------------------------------------------------
// QKV: M=16384, N=192, K=1024. Grid (512 rowtiles), 256 thr.
// Block: 32 rows x 192 cols (X read ONCE). Wave w: rows (w&1)*16,
// cols (w>>1)*96 (6 tiles). LDS 64 KB (X dbuf 16 + W dbuf 48) -> 2 blk/CU.
// ---------------------------------------------------------------------------
__global__ __launch_bounds__(256, 2) void qkv_kernel(
    const float* __restrict__ X, const unsigned short* __restrict__ wt,
    unsigned short* __restrict__ qg, unsigned short* __restrict__ kg,
    unsigned short* __restrict__ vtile)
{
    // layout: X dbuf 2x8 KB | W dbuf 2x24 KB
    __shared__ __align__(16) unsigned char smem[2 * 8192 + 2 * 24576];
    unsigned short* vstage = (unsigned short*)smem;   // 5 KB alias, post-loop

    const int t = (int)threadIdx.x;
    const int w = t >> 6, lane = t & 63;
    const int l15 = lane & 15, quad = lane >> 4;
    const int r0 = (int)blockIdx.x * 32;
    const int rbase = (w & 1) * 16;
    const int nloc0 = (w >> 1) * 96;

    const int wrow_off = lane >> 3, wgs = lane & 7;

    floatx4 acc[6];
#pragma unroll
    for (int j = 0; j < 6; j++) acc[j] = (floatx4){0.f, 0.f, 0.f, 0.f};

#define XBUF(q) (smem + (q) * 8192)
#define WBUF(q) (smem + 16384 + (q) * 24576)
    // X: 512 granules/chunk (32 rows x 16); wave w: gi = w*128 + j*64 + lane
#define STAGE_X(c, q) do {                                                   \
        _Pragma("unroll")                                                    \
        for (int j = 0; j < 2; j++) {                                        \
            const int gi = w * 128 + j * 64 + lane;                          \
            const int row = gi >> 4;                                         \
            const int g = (gi & 15) ^ (row & 15);                            \
            load_lds16(X + (size_t)(r0 + row) * E_ + (c) * 64 + g * 4,       \
                       XBUF(q) + (w * 128 + j * 64) * 16);                   \
        }                                                                    \
    } while (0)
    // W: 192 rows x 8 granules; 24 regions of 8 rows; wave w: regions w*6+j
#define STAGE_W(c, q) do {                                                   \
        _Pragma("unroll")                                                    \
        for (int j = 0; j < 6; j++) {                                        \
            const int region = w * 6 + j;                                    \
            const int nloc = region * 8 + wrow_off;                          \
            const int gsrc = wgs ^ (nloc & 7);                               \
            load_lds16(wt + (size_t)nloc * 1024 + (c) * 64 + gsrc * 8,       \
                       WBUF(q) + region * 1024);                             \
        }                                                                    \
    } while (0)

    STAGE_X(0, 0);
    STAGE_W(0, 0);

#pragma unroll
    for (int c = 0; c < 16; c++) {
        __syncthreads();   // drains DMA issued last iter (vmcnt(0) structural)
        if (c + 1 < 16) {
            STAGE_X(c + 1, (c + 1) & 1);
            STAGE_W(c + 1, (c + 1) & 1);
        }
        const float4* xc = (const float4*)XBUF(c & 1);
        const unsigned short* wc = (const unsigned short*)WBUF(c & 1);

#pragma unroll
        for (int ks = 0; ks < 2; ks++) {
            const int g0 = ks * 8 + quad * 2;
            const float4* xrow = xc + (rbase + l15) * 16;
            float4 f0 = xrow[g0 ^ l15];
            float4 f1 = xrow[(g0 + 1) ^ l15];
            BF8 a;
            a.u[0] = pack_bf2(f0.x, f0.y);
            a.u[1] = pack_bf2(f0.z, f0.w);
            a.u[2] = pack_bf2(f1.x, f1.y);
            a.u[3] = pack_bf2(f1.z, f1.w);
#pragma unroll
            for (int nt = 0; nt < 6; nt++) {
                const int nloc = nloc0 + nt * 16 + l15;
                const int slot = (ks * 4 + quad) ^ (nloc & 7);
                short8 bfr = *(const short8*)(wc + nloc * 64 + slot * 8);
                acc[nt] = __builtin_amdgcn_mfma_f32_16x16x32_bf16(
                    a.s8, bfr, acc[nt], 0, 0, 0);
            }
        }
    }
#undef STAGE_X
#undef STAGE_W
#undef XBUF
#undef WBUF

    // epilogue (C/D: row = rbase + quad*4 + r, col n = nloc0 + nt*16 + l15)
    const int bb = r0 >> 11;
    const int keybase = r0 & 2047;
    const int rowl0 = rbase + quad * 4;
    __syncthreads();   // all LDS reads done; safe to alias vstage
#pragma unroll
    for (int nt = 0; nt < 6; nt++) {
        const int n = nloc0 + nt * 16 + l15;
        if (n < 64) {
#pragma unroll
            for (int r = 0; r < 4; r++)
                qg[(size_t)(r0 + rowl0 + r) * 64 + n] = f2bf(acc[nt][r] * SCALE);
        } else if (n < 128) {
#pragma unroll
            for (int r = 0; r < 4; r++)
                kg[(size_t)(r0 + rowl0 + r) * 64 + (n - 64)] = f2bf(acc[nt][r]);
        } else {
            const int h = n - 128;
            *(unsigned int*)&vstage[h * 40 + rowl0] =
                pack_bf2(acc[nt][0], acc[nt][1]);
            *(unsigned int*)&vstage[h * 40 + rowl0 + 2] =
                pack_bf2(acc[nt][2], acc[nt][3]);
        }
    }
    __syncthreads();
    // V tile: 64 h x 32 keys -> vtile[b][kb][h][64key]
    {
        const int h = t >> 2, part = t & 3;
        uint4 v = *(const uint4*)&vstage[h * 40 + part * 8];
        *(uint4*)(vtile + ((size_t)(bb * 32 + (keybase >> 6)) * 64 + h) * 64
                  + (keybase & 63) + part * 8) = v;
    }
}

// ---------------------------------------------------------------------------
// Attention split-K. Grid (8, 32, 4); 256 thr (4 waves); 64 q-rows/block.
// Split z covers key-tiles [8z, min(8z+8,nkt)). K/V dbuf via swizzled DMA.
// q0<512 (ns==1): direct normalized out. Else unnormalized partials.
// ---------------------------------------------------------------------------
__global__ __launch_bounds__(256, 3) void attn_kernel(
    const unsigned short* __restrict__ qg, const unsigned short* __restrict__ kg,
    const unsigned short* __restrict__ vtile, const int* __restrict__ zmask,
    float* __restrict__ opart, float* __restrict__ lpart,
    float* __restrict__ out)
{
    __shared__ unsigned short Klds[2][64 * 64];  // swizzled [key][64h]
    __shared__ unsigned short Vlds[2][64 * 64];  // swizzled [h][64key]
    __shared__ unsigned short Ps[64 * 88];       // per-wave-private rows

    const int t = (int)threadIdx.x;
    const int w = t >> 6, lane = t & 63;
    const int l15 = lane & 15, quad = lane >> 4;
    const int b = (int)blockIdx.x;
    const int qt = (int)blockIdx.y;            // 64-row q-tile, 0..31
    const int z = (int)blockIdx.z;
    const int q0 = qt * 64;
    const int nkt = qt + 1;                    // key-tiles needed (causal)
    const int t0 = z * 8;
    const int t1 = (t0 + 8 < nkt) ? (t0 + 8) : nkt;
    if (t0 >= t1) return;
    const int ns = (nkt + 7) >> 3;

    const int qlo = q0 + w * 16;
    const int myrow = qlo + quad * 4;
    const int srow_off = lane >> 3, sgs = lane & 7;

    short8 qfr[2];
#pragma unroll
    for (int kc = 0; kc < 2; kc++)
        qfr[kc] = *(const short8*)(qg + ((size_t)b * C_ + qlo + l15) * 64
                                   + kc * 32 + quad * 8);

    floatx4 accO[4];
#pragma unroll
    for (int i = 0; i < 4; i++) accO[i] = (floatx4){0.f, 0.f, 0.f, 0.f};
    float lsum[4] = {0.f, 0.f, 0.f, 0.f};

    // stage tile t0 into buf 0 (8 regions of 8 rows; wave w: regions 2w,2w+1)
#pragma unroll
    for (int j = 0; j < 2; j++) {
        const int region = w * 2 + j;
        const int row = region * 8 + srow_off;
        const int gsrc = sgs ^ (row & 7);
        load_lds16(kg + ((size_t)b * C_ + t0 * 64 + row) * 64 + gsrc * 8,
                   &Klds[0][region * 512]);
        load_lds16(vtile + (((size_t)b * 32 + t0) * 64 + row) * 64 + gsrc * 8,
                   &Vlds[0][region * 512]);
    }

    int buf = 0;
    for (int kt = t0; kt < t1; kt++) {
        __syncthreads();
        if (kt + 1 < t1) {
            const int k0n = (kt + 1) * 64;
#pragma unroll
            for (int j = 0; j < 2; j++) {
                const int region = w * 2 + j;
                const int row = region * 8 + srow_off;
                const int gsrc = sgs ^ (row & 7);
                load_lds16(kg + ((size_t)b * C_ + k0n + row) * 64 + gsrc * 8,
                           &Klds[buf ^ 1][region * 512]);
                load_lds16(vtile + (((size_t)b * 32 + kt + 1) * 64 + row) * 64 + gsrc * 8,
                           &Vlds[buf ^ 1][region * 512]);
            }
        }

        floatx4 s[4];
#pragma unroll
        for (int nt = 0; nt < 4; nt++) {
            const int row = nt * 16 + l15;
            short8 kf0 = *(const short8*)&Klds[buf][row * 64 + ((quad) ^ (row & 7)) * 8];
            short8 kf1 = *(const short8*)&Klds[buf][row * 64 + ((4 + quad) ^ (row & 7)) * 8];
            floatx4 zz = (floatx4){0.f, 0.f, 0.f, 0.f};
            zz = __builtin_amdgcn_mfma_f32_16x16x32_bf16(qfr[0], kf0, zz, 0, 0, 0);
            s[nt] = __builtin_amdgcn_mfma_f32_16x16x32_bf16(qfr[1], kf1, zz, 0, 0, 0);
        }
        float pr[4][4];
#pragma unroll
        for (int nt = 0; nt < 4; nt++)
#pragma unroll
            for (int r = 0; r < 4; r++)
                pr[nt][r] = __builtin_amdgcn_exp2f(s[nt][r]);
        if (kt == nkt - 1) {   // diagonal tile (only in last split)
            const int k0 = kt * 64;
#pragma unroll
            for (int nt = 0; nt < 4; nt++) {
                const int key = k0 + nt * 16 + l15;
#pragma unroll
                for (int r = 0; r < 4; r++)
                    if (key > myrow + r) pr[nt][r] = 0.f;
            }
        }
#pragma unroll
        for (int nt = 0; nt < 4; nt++)
#pragma unroll
            for (int r = 0; r < 4; r++) {
                lsum[r] += pr[nt][r];
                Ps[(w * 16 + quad * 4 + r) * 88 + nt * 16 + l15] = f2bf(pr[nt][r]);
            }
#pragma unroll
        for (int kc = 0; kc < 2; kc++) {
            short8 af = *(const short8*)&Ps[(w * 16 + l15) * 88 + kc * 32 + quad * 8];
#pragma unroll
            for (int nt = 0; nt < 4; nt++) {
                const int row = nt * 16 + l15;
                short8 vf = *(const short8*)&Vlds[buf][row * 64
                                + ((kc * 4 + quad) ^ (row & 7)) * 8];
                accO[nt] = __builtin_amdgcn_mfma_f32_16x16x32_bf16(
                    af, vf, accO[nt], 0, 0, 0);
            }
        }
        buf ^= 1;
    }

    // reduce l across the 16 col-lanes
#pragma unroll
    for (int r = 0; r < 4; r++) {
        float v = lsum[r];
        v += __shfl_xor(v, 1);
        v += __shfl_xor(v, 2);
        v += __shfl_xor(v, 4);
        v += __shfl_xor(v, 8);
        lsum[r] = v;
    }

    if (ns == 1) {
        float inv[4];
#pragma unroll
        for (int r = 0; r < 4; r++) {
            int zm = zmask[b * C_ + myrow + r];
            inv[r] = zm ? 0.f : 1.0f / lsum[r];
        }
#pragma unroll
        for (int nt = 0; nt < 4; nt++)
#pragma unroll
            for (int r = 0; r < 4; r++)
                out[(size_t)(b * C_ + myrow + r) * 64 + nt * 16 + l15] =
                    accO[nt][r] * inv[r];
    } else {
        // partials (myrow >= 512): opart[z][b][row-512][h]
        const int lrow = myrow - 512;
        float* ob = opart + ((size_t)(z * 8 + b) * 1536 + lrow) * 64;
#pragma unroll
        for (int nt = 0; nt < 4; nt++)
#pragma unroll
            for (int r = 0; r < 4; r++)
                ob[(size_t)r * 64 + nt * 16 + l15] = accO[nt][r];
        if (l15 == 0) {
#pragma unroll
            for (int r = 0; r < 4; r++)
                lpart[(size_t)(z * 8 + b) * 1536 + lrow + r] = lsum[r];
        }
    }
}

// ---------------------------------------------------------------------------
// Combine rows >= 512: out = sum_z O_z / sum_z l_z, zmask applied.
// Grid (96, 8): 8 b x 1536 rows x 16 float4.
// ---------------------------------------------------------------------------
__global__ __launch_bounds__(256) void combine_kernel(
    const float* __restrict__ opart, const float* __restrict__ lpart,
    const int* __restrict__ zmask, float* __restrict__ out)
{
    const int b = (int)blockIdx.y;
    const int gid = (int)blockIdx.x * 256 + (int)threadIdx.x;  // 0..24575
    const int lrow = gid >> 4;         // 0..1535
    const int f4 = gid & 15;
    const int row = 512 + lrow;
    const int nkt = (row >> 6) + 1;
    const int ns = (nkt + 7) >> 3;     // 2..4

    float4 o = make_float4(0.f, 0.f, 0.f, 0.f);
    float l = 0.f;
    for (int zc = 0; zc < ns; zc++) {
        float4 p = *(const float4*)(opart
            + ((size_t)(zc * 8 + b) * 1536 + lrow) * 64 + f4 * 4);
        o.x += p.x; o.y += p.y; o.z += p.z; o.w += p.w;
        l += lpart[(size_t)(zc * 8 + b) * 1536 + lrow];
    }
    const float inv = zmask[b * C_ + row] ? 0.f : 1.0f / l;
    *(float4*)(out + (size_t)(b * C_ + row) * 64 + f4 * 4) =
        make_float4(o.x * inv, o.y * inv, o.z * inv, o.w * inv);
}

// ---------------------------------------------------------------------------
extern "C" void kernel_launch(void* const* d_in, const int* in_sizes, int n_in,
                              void* d_out, int out_size, void* d_ws, size_t ws_size,
                              hipStream_t stream) {
    const float* X  = (const float*)d_in[0];
    const float* Wq = (const float*)d_in[1];
    const float* Wk = (const float*)d_in[2];
    const float* Wv = (const float*)d_in[3];
    const int*   zm = (const int*)d_in[4];
    float* out = (float*)d_out;

    unsigned short* qg    = (unsigned short*)d_ws;               // 2 MB
    unsigned short* kg    = qg    + (size_t)B_ * C_ * H_;        // 2 MB
    unsigned short* vtile = kg    + (size_t)B_ * C_ * H_;        // 2 MB
    unsigned short* wt    = vtile + (size_t)B_ * C_ * H_;        // 384 KB
    float* opart = (float*)(wt + (size_t)192 * 1024);            // 12.6 MB
    float* lpart = opart + (size_t)4 * 8 * 1536 * 64;            // 192 KB

    wcvt_kernel<<<dim3(48), dim3(256), 0, stream>>>(Wq, Wk, Wv, wt);
    qkv_kernel<<<dim3(512), dim3(256), 0, stream>>>(X, wt, qg, kg, vtile);
    attn_kernel<<<dim3(B_, 32, 4), dim3(256), 0, stream>>>(
        qg, kg, vtile, zm, opart, lpart, out);
    combine_kernel<<<dim3(96, B_), dim3(256), 0, stream>>>(opart, lpart, zm, out);
}